// Round 1
// baseline (837.670 us; speedup 1.0000x reference)
//
#include <hip/hip_runtime.h>
#include <math.h>

constexpr int kD      = 768;
constexpr int kNH     = 12;
constexpr int kDK     = 64;
constexpr int kFF     = 3072;
constexpr int kPH     = 32;     // POS_HIDDEN
constexpr int kB      = 2;
constexpr int kL      = 1024;
constexpr int kRows   = kB * kL;   // 2048
constexpr float kEPS  = 1e-5f;

// ---------------------------------------------------------------------------
// Generic tiled fp32 GEMM:  C[M,N] = op(A[M,K] @ W[K,N] + bias)   (op = id / relu)
// 64x64 tile, BK=16, 256 threads, 4x4 per thread.
// ---------------------------------------------------------------------------
template<int RELU>
__global__ __launch_bounds__(256)
void gemm_kernel(const float* __restrict__ A, const float* __restrict__ W,
                 const float* __restrict__ bias, float* __restrict__ C,
                 int M, int N, int K)
{
    __shared__ float As[16][68];   // transposed A tile, padded (+4) for conflict-free b128
    __shared__ float Bs[16][64];

    const int tid  = threadIdx.x;
    const int tx   = tid & 15;
    const int ty   = tid >> 4;
    const int row0 = blockIdx.y * 64;
    const int col0 = blockIdx.x * 64;

    // global-load index split (one float4 per thread per tile)
    const int ar  = tid >> 2;   // 0..63 (A row within tile)
    const int ac4 = tid & 3;    // 0..3  (A col group of 4)
    const int br  = tid >> 4;   // 0..15 (B k-row within tile)
    const int bc4 = tid & 15;   // 0..15 (B col group of 4)

    float acc[4][4] = {};

    for (int k0 = 0; k0 < K; k0 += 16) {
        const float4 av = *(const float4*)&A[(size_t)(row0 + ar) * K + k0 + ac4 * 4];
        const float4 bv = *(const float4*)&W[(size_t)(k0 + br) * N + col0 + bc4 * 4];
        __syncthreads();   // previous iteration's LDS reads complete
        As[ac4 * 4 + 0][ar] = av.x;
        As[ac4 * 4 + 1][ar] = av.y;
        As[ac4 * 4 + 2][ar] = av.z;
        As[ac4 * 4 + 3][ar] = av.w;
        *(float4*)&Bs[br][bc4 * 4] = bv;
        __syncthreads();

        #pragma unroll
        for (int kk = 0; kk < 16; ++kk) {
            const float4 ra4 = *(const float4*)&As[kk][ty * 4];
            const float4 rb4 = *(const float4*)&Bs[kk][tx * 4];
            const float ra[4] = {ra4.x, ra4.y, ra4.z, ra4.w};
            const float rb[4] = {rb4.x, rb4.y, rb4.z, rb4.w};
            #pragma unroll
            for (int i = 0; i < 4; ++i)
                #pragma unroll
                for (int j = 0; j < 4; ++j)
                    acc[i][j] = fmaf(ra[i], rb[j], acc[i][j]);
        }
    }

    #pragma unroll
    for (int i = 0; i < 4; ++i) {
        const int r = row0 + ty * 4 + i;
        const int c = col0 + tx * 4;
        float4 out;
        out.x = acc[i][0] + bias[c + 0];
        out.y = acc[i][1] + bias[c + 1];
        out.z = acc[i][2] + bias[c + 2];
        out.w = acc[i][3] + bias[c + 3];
        if (RELU) {
            out.x = fmaxf(out.x, 0.f); out.y = fmaxf(out.y, 0.f);
            out.z = fmaxf(out.z, 0.f); out.w = fmaxf(out.w, 0.f);
        }
        *(float4*)&C[(size_t)r * N + c] = out;
    }
}

// ---------------------------------------------------------------------------
// Flash-style attention with fused relative-position-bias MLP.
// grid = (B*NHEAD, L/32), block = 256.  Each block: one (b,h), 32 q-rows.
// Thread layout: ty = tid>>3 (q-row 0..31), tx = tid&7.
// S columns per thread: j = tx + 8*jj, jj=0..3.  O dims per thread: tx*8 .. tx*8+7.
// ---------------------------------------------------------------------------
__global__ __launch_bounds__(256)
void attn_kernel(const float* __restrict__ qg, const float* __restrict__ kg,
                 const float* __restrict__ vg,
                 const float* __restrict__ sx, const float* __restrict__ sy,
                 const float* __restrict__ P1, const float* __restrict__ pb1,
                 const float* __restrict__ P2, const float* __restrict__ pb2,
                 float* __restrict__ og)
{
    constexpr int QT = 32, KT = 32, STR = 68;  // padded LDS stride for 64-float rows

    const int bh = blockIdx.x;
    const int b  = bh / kNH;
    const int h  = bh - b * kNH;
    const int q0 = blockIdx.y * QT;
    const int tid = threadIdx.x;
    const int ty = tid >> 3;   // q row 0..31
    const int tx = tid & 7;    // 0..7

    __shared__ float Ql[QT][STR];
    __shared__ float Kl[KT][STR];
    __shared__ float Vl[KT][STR];
    __shared__ float Sp[QT][KT + 1];
    __shared__ float qx[QT], qy[QT], kx[KT], ky[KT];
    __shared__ float p1a[kPH], p1b[kPH], pc1[kPH], p2c[kPH];

    if (tid < kPH) {
        p1a[tid] = P1[tid];             // P1[0][u]
        p1b[tid] = P1[kPH + tid];       // P1[1][u]
        pc1[tid] = pb1[tid];
        p2c[tid] = P2[tid * kNH + h];   // P2[u][h]
    }
    if (tid < QT) {
        qx[tid] = sx[b * kL + q0 + tid];
        qy[tid] = sy[b * kL + q0 + tid];
    }
    // Q tile (scaled by 1/sqrt(dk) = 0.125)
    for (int i = tid; i < QT * (kDK / 4); i += 256) {
        const int r  = i >> 4;
        const int c4 = i & 15;
        const float4 t = *(const float4*)&qg[(size_t)(b * kL + q0 + r) * kD + h * kDK + c4 * 4];
        Ql[r][c4 * 4 + 0] = t.x * 0.125f;
        Ql[r][c4 * 4 + 1] = t.y * 0.125f;
        Ql[r][c4 * 4 + 2] = t.z * 0.125f;
        Ql[r][c4 * 4 + 3] = t.w * 0.125f;
    }

    float m_run = -INFINITY;
    float l_run = 0.f;
    float accO[8] = {};

    const float pb2h = pb2[h];

    for (int k0 = 0; k0 < kL; k0 += KT) {
        __syncthreads();   // prior tile's consumers done (also publishes preamble on iter 0)
        for (int i = tid; i < KT * (kDK / 4); i += 256) {
            const int r  = i >> 4;
            const int c4 = i & 15;
            const size_t base = (size_t)(b * kL + k0 + r) * kD + h * kDK + c4 * 4;
            const float4 tk = *(const float4*)&kg[base];
            const float4 tv = *(const float4*)&vg[base];
            Kl[r][c4 * 4 + 0] = tk.x; Kl[r][c4 * 4 + 1] = tk.y;
            Kl[r][c4 * 4 + 2] = tk.z; Kl[r][c4 * 4 + 3] = tk.w;
            Vl[r][c4 * 4 + 0] = tv.x; Vl[r][c4 * 4 + 1] = tv.y;
            Vl[r][c4 * 4 + 2] = tv.z; Vl[r][c4 * 4 + 3] = tv.w;
        }
        if (tid < KT) {
            kx[tid] = sx[b * kL + k0 + tid];
            ky[tid] = sy[b * kL + k0 + tid];
        }
        __syncthreads();

        // ---- scores: s[jj] = (q . k_j)  (q pre-scaled) ----
        float s[4] = {};
        #pragma unroll
        for (int d4 = 0; d4 < 16; ++d4) {
            const float4 qv = *(const float4*)&Ql[ty][d4 * 4];
            #pragma unroll
            for (int jj = 0; jj < 4; ++jj) {
                const float4 kv = *(const float4*)&Kl[tx + 8 * jj][d4 * 4];
                s[jj] = fmaf(qv.x, kv.x, s[jj]);
                s[jj] = fmaf(qv.y, kv.y, s[jj]);
                s[jj] = fmaf(qv.z, kv.z, s[jj]);
                s[jj] = fmaf(qv.w, kv.w, s[jj]);
            }
        }

        // ---- relative-position bias MLP ----
        float rxv[4], ryv[4];
        const float qxv = qx[ty], qyv = qy[ty];
        #pragma unroll
        for (int jj = 0; jj < 4; ++jj) {
            const int j = tx + 8 * jj;
            float dx = qxv - kx[j];
            float dy = qyv - ky[j];
            dx = fminf(fmaxf(dx, -1000.f), 1000.f);
            dy = fminf(fmaxf(dy, -1000.f), 1000.f);
            rxv[jj] = dx * 1e-3f;
            ryv[jj] = dy * 1e-3f;
        }
        #pragma unroll
        for (int u = 0; u < kPH; ++u) {
            const float a = p1a[u], bb = p1b[u], c = pc1[u], w = p2c[u];
            #pragma unroll
            for (int jj = 0; jj < 4; ++jj) {
                float t = fmaf(rxv[jj], a, fmaf(ryv[jj], bb, c));
                t = fmaxf(t, 0.f);
                s[jj] = fmaf(t, w, s[jj]);
            }
        }
        #pragma unroll
        for (int jj = 0; jj < 4; ++jj) s[jj] += pb2h;

        // ---- online softmax (row = 8 lanes sharing ty) ----
        float tmax = fmaxf(fmaxf(s[0], s[1]), fmaxf(s[2], s[3]));
        tmax = fmaxf(tmax, __shfl_xor(tmax, 1, 8));
        tmax = fmaxf(tmax, __shfl_xor(tmax, 2, 8));
        tmax = fmaxf(tmax, __shfl_xor(tmax, 4, 8));
        const float mnew  = fmaxf(m_run, tmax);
        const float alpha = __expf(m_run - mnew);   // 0 on first tile (-inf - finite)
        float lsum = 0.f;
        #pragma unroll
        for (int jj = 0; jj < 4; ++jj) {
            const float p = __expf(s[jj] - mnew);
            lsum += p;
            Sp[ty][tx + 8 * jj] = p;
        }
        lsum += __shfl_xor(lsum, 1, 8);
        lsum += __shfl_xor(lsum, 2, 8);
        lsum += __shfl_xor(lsum, 4, 8);
        l_run = l_run * alpha + lsum;
        m_run = mnew;
        #pragma unroll
        for (int c = 0; c < 8; ++c) accO[c] *= alpha;
        __syncthreads();   // Sp visible

        // ---- O += P @ V ----
        #pragma unroll
        for (int j = 0; j < KT; ++j) {
            const float pj = Sp[ty][j];
            const float4 v0 = *(const float4*)&Vl[j][tx * 8];
            const float4 v1 = *(const float4*)&Vl[j][tx * 8 + 4];
            accO[0] = fmaf(pj, v0.x, accO[0]);
            accO[1] = fmaf(pj, v0.y, accO[1]);
            accO[2] = fmaf(pj, v0.z, accO[2]);
            accO[3] = fmaf(pj, v0.w, accO[3]);
            accO[4] = fmaf(pj, v1.x, accO[4]);
            accO[5] = fmaf(pj, v1.y, accO[5]);
            accO[6] = fmaf(pj, v1.z, accO[6]);
            accO[7] = fmaf(pj, v1.w, accO[7]);
        }
    }

    const float inv = 1.0f / l_run;
    const size_t obase = (size_t)(b * kL + q0 + ty) * kD + h * kDK + tx * 8;
    float4 o0, o1;
    o0.x = accO[0] * inv; o0.y = accO[1] * inv; o0.z = accO[2] * inv; o0.w = accO[3] * inv;
    o1.x = accO[4] * inv; o1.y = accO[5] * inv; o1.z = accO[6] * inv; o1.w = accO[7] * inv;
    *(float4*)&og[obase]     = o0;
    *(float4*)&og[obase + 4] = o1;
}

// ---------------------------------------------------------------------------
// Residual + LayerNorm: out = LN(a + r) * g + be     (one block per row)
// ---------------------------------------------------------------------------
__global__ __launch_bounds__(256)
void ln_kernel(const float* __restrict__ a, const float* __restrict__ r,
               const float* __restrict__ g, const float* __restrict__ be,
               float* __restrict__ out)
{
    const int row = blockIdx.x;
    const int tid = threadIdx.x;
    const float* pa = a + (size_t)row * kD;
    const float* pr = r + (size_t)row * kD;

    float v[3];
    float s = 0.f, sq = 0.f;
    #pragma unroll
    for (int i = 0; i < 3; ++i) {
        const int d = tid + i * 256;
        v[i] = pa[d] + pr[d];
        s  += v[i];
        sq += v[i] * v[i];
    }
    #pragma unroll
    for (int off = 32; off > 0; off >>= 1) {
        s  += __shfl_down(s, off);
        sq += __shfl_down(sq, off);
    }
    __shared__ float bs[4], bq[4];
    if ((tid & 63) == 0) { bs[tid >> 6] = s; bq[tid >> 6] = sq; }
    __syncthreads();
    const float ts = bs[0] + bs[1] + bs[2] + bs[3];
    const float tq = bq[0] + bq[1] + bq[2] + bq[3];
    const float invn = 1.0f / (float)kD;
    const float mean = ts * invn;
    const float var  = tq * invn - mean * mean;
    const float rstd = rsqrtf(var + kEPS);

    float* po = out + (size_t)row * kD;
    #pragma unroll
    for (int i = 0; i < 3; ++i) {
        const int d = tid + i * 256;
        po[d] = (v[i] - mean) * rstd * g[d] + be[d];
    }
}

// ---------------------------------------------------------------------------
extern "C" void kernel_launch(void* const* d_in, const int* in_sizes, int n_in,
                              void* d_out, int out_size, void* d_ws, size_t ws_size,
                              hipStream_t stream)
{
    const float* src = (const float*)d_in[0];
    const float* sx  = (const float*)d_in[1];
    const float* sy  = (const float*)d_in[2];
    const float* Wq  = (const float*)d_in[3];  const float* bq  = (const float*)d_in[4];
    const float* Wk  = (const float*)d_in[5];  const float* bk  = (const float*)d_in[6];
    const float* Wv  = (const float*)d_in[7];  const float* bv  = (const float*)d_in[8];
    const float* Wo  = (const float*)d_in[9];  const float* bo  = (const float*)d_in[10];
    const float* P1  = (const float*)d_in[11]; const float* pb1 = (const float*)d_in[12];
    const float* P2  = (const float*)d_in[13]; const float* pb2 = (const float*)d_in[14];
    const float* W1  = (const float*)d_in[15]; const float* b1  = (const float*)d_in[16];
    const float* W2  = (const float*)d_in[17]; const float* b2  = (const float*)d_in[18];
    const float* g1  = (const float*)d_in[19]; const float* be1 = (const float*)d_in[20];
    const float* g2  = (const float*)d_in[21]; const float* be2 = (const float*)d_in[22];

    float* ws = (float*)d_ws;
    const size_t nBLD = (size_t)kRows * kD;   // 1,572,864 floats
    float* qb  = ws;
    float* kb  = qb + nBLD;
    float* vb  = kb + nBLD;
    float* ob  = vb + nBLD;
    float* h1  = ob + nBLD;                   // kRows * kFF floats
    float* src2 = qb;                         // alias: qb free after attention
    float* xb   = kb;                         // alias: kb free after attention
    float* ff2  = vb;                         // alias: vb free after attention

    const dim3 blk(256);
    const dim3 g768(kD / 64, kRows / 64);     // (12, 32)
    const dim3 gff (kFF / 64, kRows / 64);    // (48, 32)
    const dim3 gattn(kB * kNH, kL / 32);      // (24, 32)

    gemm_kernel<0><<<g768, blk, 0, stream>>>(src, Wq, bq, qb, kRows, kD, kD);
    gemm_kernel<0><<<g768, blk, 0, stream>>>(src, Wk, bk, kb, kRows, kD, kD);
    gemm_kernel<0><<<g768, blk, 0, stream>>>(src, Wv, bv, vb, kRows, kD, kD);

    attn_kernel<<<gattn, blk, 0, stream>>>(qb, kb, vb, sx, sy, P1, pb1, P2, pb2, ob);

    gemm_kernel<0><<<g768, blk, 0, stream>>>(ob, Wo, bo, src2, kRows, kD, kD);
    ln_kernel<<<dim3(kRows), blk, 0, stream>>>(src, src2, g1, be1, xb);

    gemm_kernel<1><<<gff,  blk, 0, stream>>>(xb, W1, b1, h1, kRows, kFF, kD);
    gemm_kernel<0><<<g768, blk, 0, stream>>>(h1, W2, b2, ff2, kRows, kD, kFF);
    ln_kernel<<<dim3(kRows), blk, 0, stream>>>(xb, ff2, g2, be2, (float*)d_out);
}

// Round 2
// 467.272 us; speedup vs baseline: 1.7927x; 1.7927x over previous
//
#include <hip/hip_runtime.h>
#include <math.h>

typedef unsigned short ushort_t;
typedef __attribute__((ext_vector_type(8))) short bf16x8;
typedef __attribute__((ext_vector_type(4))) float f32x4;

constexpr int kD      = 768;
constexpr int kNH     = 12;
constexpr int kDK     = 64;
constexpr int kFF     = 3072;
constexpr int kPH     = 32;
constexpr int kL      = 1024;
constexpr int kRows   = 2048;     // B * L
constexpr float kEPS  = 1e-5f;

__device__ __forceinline__ ushort_t f2bf(float f) {
    union { float f; unsigned u; } v; v.f = f;
    unsigned r = (v.u + 0x7fffu + ((v.u >> 16) & 1u)) >> 16;
    return (ushort_t)r;
}
__device__ __forceinline__ float bf2f(ushort_t u) {
    union { unsigned u; float f; } v; v.u = ((unsigned)u) << 16; return v.f;
}

#define GL_LDS(gp, lp) __builtin_amdgcn_global_load_lds( \
    (const __attribute__((address_space(1))) void*)(gp), \
    (__attribute__((address_space(3))) void*)(lp), 16, 0, 0)

// ---------------------------------------------------------------------------
// bf16 MFMA GEMM, m97 structure: 128x128 tile, BK=32, 4 waves, 2-barrier
// K-loop with global_load_lds width=16.  A[M,K] bf16 row-major, WT[N,K] bf16
// (pre-transposed weights), C = A @ W + bias (optional relu / bf16 out).
// ---------------------------------------------------------------------------
template<int RELU, int OUTBF>
__device__ __forceinline__ void gemm_body(const ushort_t* __restrict__ A,
                                          const ushort_t* __restrict__ WT,
                                          const float* __restrict__ bias,
                                          void* __restrict__ Cout,
                                          int N, int K, int row0, int col0)
{
    __shared__ ushort_t lds[8192];          // As 128x32 | Bs 128x32 (bf16)
    ushort_t* As = lds;
    ushort_t* Bs = lds + 4096;

    const int tid  = threadIdx.x;
    const int lane = tid & 63;
    const int wave = tid >> 6;
    const int wrow = (wave & 1) * 64;
    const int wcol = (wave >> 1) * 64;

    // staging: per instr, wave covers 16 rows x 32 k (1 KiB); lane = 4/row
    const int srow = wave * 16 + (lane >> 2);
    const int sk   = (lane & 3) * 8;
    const ushort_t* ga0 = A  + (size_t)(row0 + srow)      * K + sk;
    const ushort_t* ga1 = A  + (size_t)(row0 + srow + 64) * K + sk;
    const ushort_t* gb0 = WT + (size_t)(col0 + srow)      * K + sk;
    const ushort_t* gb1 = WT + (size_t)(col0 + srow + 64) * K + sk;
    ushort_t* la0 = As + wave * 512;
    ushort_t* la1 = As + 2048 + wave * 512;
    ushort_t* lb0 = Bs + wave * 512;
    ushort_t* lb1 = Bs + 2048 + wave * 512;

    // fragment pointers (loop-invariant)
    const int fl = lane & 15, fq = lane >> 4;
    const ushort_t* fa[4];
    const ushort_t* fb[4];
    #pragma unroll
    for (int i = 0; i < 4; ++i) {
        fa[i] = As + (wrow + i * 16 + fl) * 32 + fq * 8;
        fb[i] = Bs + (wcol + i * 16 + fl) * 32 + fq * 8;
    }

    f32x4 acc[4][4] = {};

    for (int k0 = 0; k0 < K; k0 += 32) {
        __syncthreads();                  // prior frag reads done
        GL_LDS(ga0 + k0, la0);
        GL_LDS(ga1 + k0, la1);
        GL_LDS(gb0 + k0, lb0);
        GL_LDS(gb1 + k0, lb1);
        __syncthreads();                  // compiler drains vmcnt before barrier

        bf16x8 av[4], bv[4];
        #pragma unroll
        for (int i = 0; i < 4; ++i) {
            av[i] = *(const bf16x8*)fa[i];
            bv[i] = *(const bf16x8*)fb[i];
        }
        #pragma unroll
        for (int mi = 0; mi < 4; ++mi)
            #pragma unroll
            for (int ni = 0; ni < 4; ++ni)
                acc[mi][ni] = __builtin_amdgcn_mfma_f32_16x16x32_bf16(
                    av[mi], bv[ni], acc[mi][ni], 0, 0, 0);
    }

    // epilogue: C/D layout col=lane&15, row=(lane>>4)*4+r
    #pragma unroll
    for (int mi = 0; mi < 4; ++mi) {
        const int m = wrow + mi * 16 + fq * 4;
        #pragma unroll
        for (int ni = 0; ni < 4; ++ni) {
            const int n = wcol + ni * 16 + fl;
            const float bb = bias[col0 + n];
            #pragma unroll
            for (int r = 0; r < 4; ++r) {
                float v = acc[mi][ni][r] + bb;
                if (RELU) v = fmaxf(v, 0.f);
                const size_t idx = (size_t)(row0 + m + r) * N + col0 + n;
                if (OUTBF) ((ushort_t*)Cout)[idx] = f2bf(v);
                else       ((float*)Cout)[idx]    = v;
            }
        }
    }
}

template<int RELU, int OUTBF>
__global__ __launch_bounds__(256)
void gemm_kernel(const ushort_t* __restrict__ A, const ushort_t* __restrict__ WT,
                 const float* __restrict__ bias, void* __restrict__ Cout,
                 int N, int K)
{
    gemm_body<RELU, OUTBF>(A, WT, bias, Cout, N, K, blockIdx.y * 128, blockIdx.x * 128);
}

__global__ __launch_bounds__(256)
void gemm_qkv_kernel(const ushort_t* __restrict__ A,
                     const ushort_t* wq, const ushort_t* wk, const ushort_t* wv,
                     const float* bq, const float* bk, const float* bv,
                     ushort_t* q, ushort_t* k, ushort_t* v)
{
    const ushort_t* WT; const float* bias; ushort_t* out;
    if (blockIdx.z == 0)      { WT = wq; bias = bq; out = q; }
    else if (blockIdx.z == 1) { WT = wk; bias = bk; out = k; }
    else                      { WT = wv; bias = bv; out = v; }
    gemm_body<0, 1>(A, WT, bias, out, kD, kD, blockIdx.y * 128, blockIdx.x * 128);
}

// ---------------------------------------------------------------------------
// Weight transpose + fp32->bf16:  W[K][N] -> WT[N][K] bf16.  64x64 LDS tiles.
// grid = (576, 1, 6); tile id -> (kt, nt) per-weight; excess tiles exit.
// ---------------------------------------------------------------------------
struct WtDesc { const float* src; ushort_t* dst; int K; int N; };
struct WtArgs { WtDesc d[6]; };

__global__ __launch_bounds__(256)
void wt_kernel(WtArgs args)
{
    const WtDesc w = args.d[blockIdx.z];
    const int ktiles = w.K >> 6;
    const int kt = (blockIdx.x % ktiles) * 64;
    const int nt = (blockIdx.x / ktiles) * 64;
    if (nt >= w.N) return;

    __shared__ float T[64][65];
    const int tid = threadIdx.x;
    #pragma unroll
    for (int i = 0; i < 4; ++i) {
        const int e = tid + i * 256;
        const int r = e >> 4;
        const int c = (e & 15) * 4;
        const float4 f = *(const float4*)&w.src[(size_t)(kt + r) * w.N + nt + c];
        T[c + 0][r] = f.x; T[c + 1][r] = f.y; T[c + 2][r] = f.z; T[c + 3][r] = f.w;
    }
    __syncthreads();
    #pragma unroll
    for (int i = 0; i < 4; ++i) {
        const int e = tid + i * 256;
        const int n = e >> 4;
        const int kc = (e & 15) * 4;
        ushort4 o;
        o.x = f2bf(T[n][kc + 0]); o.y = f2bf(T[n][kc + 1]);
        o.z = f2bf(T[n][kc + 2]); o.w = f2bf(T[n][kc + 3]);
        *(ushort4*)&w.dst[(size_t)(nt + n) * w.K + kt + kc] = o;
    }
}

// fp32 -> bf16 elementwise (src conversion)
__global__ __launch_bounds__(256)
void cvt_kernel(const float* __restrict__ in, ushort_t* __restrict__ out, int n4)
{
    const int i = blockIdx.x * 256 + threadIdx.x;
    if (i < n4) {
        const float4 f = ((const float4*)in)[i];
        ushort4 o;
        o.x = f2bf(f.x); o.y = f2bf(f.y); o.z = f2bf(f.z); o.w = f2bf(f.w);
        ((ushort4*)out)[i] = o;
    }
}

// ---------------------------------------------------------------------------
// Flash attention + fused relative-position-bias MLP (bf16 q/k/v in, bf16 o out)
// ---------------------------------------------------------------------------
__global__ __launch_bounds__(256)
void attn_kernel(const ushort_t* __restrict__ qg, const ushort_t* __restrict__ kg,
                 const ushort_t* __restrict__ vg,
                 const float* __restrict__ sx, const float* __restrict__ sy,
                 const float* __restrict__ P1, const float* __restrict__ pb1,
                 const float* __restrict__ P2, const float* __restrict__ pb2,
                 ushort_t* __restrict__ og)
{
    constexpr int QT = 32, KT = 32, STR = 68;

    const int bh = blockIdx.x;
    const int b  = bh / kNH;
    const int h  = bh - b * kNH;
    const int q0 = blockIdx.y * QT;
    const int tid = threadIdx.x;
    const int ty = tid >> 3;
    const int tx = tid & 7;

    __shared__ float Ql[QT][STR];
    __shared__ float Kl[KT][STR];
    __shared__ float Vl[KT][STR];
    __shared__ float Sp[QT][KT + 1];
    __shared__ float qx[QT], qy[QT], kx[KT], ky[KT];
    __shared__ float p1a[kPH], p1b[kPH], pc1[kPH], p2c[kPH];

    if (tid < kPH) {
        p1a[tid] = P1[tid];
        p1b[tid] = P1[kPH + tid];
        pc1[tid] = pb1[tid];
        p2c[tid] = P2[tid * kNH + h];
    }
    if (tid < QT) {
        qx[tid] = sx[b * kL + q0 + tid];
        qy[tid] = sy[b * kL + q0 + tid];
    }
    {   // Q tile: 32x64 bf16, one uint4 (8 elems) per thread, scaled 0.125
        const int r  = tid >> 3;
        const int c8 = (tid & 7) * 8;
        const uint4 raw = *(const uint4*)&qg[(size_t)(b * kL + q0 + r) * kD + h * kDK + c8];
        const ushort_t* pr = (const ushort_t*)&raw;
        #pragma unroll
        for (int j = 0; j < 8; ++j) Ql[r][c8 + j] = bf2f(pr[j]) * 0.125f;
    }

    float m_run = -INFINITY;
    float l_run = 0.f;
    float accO[8] = {};
    const float pb2h = pb2[h];

    for (int k0 = 0; k0 < kL; k0 += KT) {
        __syncthreads();
        {
            const int r  = tid >> 3;
            const int c8 = (tid & 7) * 8;
            const size_t base = (size_t)(b * kL + k0 + r) * kD + h * kDK + c8;
            const uint4 rk = *(const uint4*)&kg[base];
            const uint4 rv = *(const uint4*)&vg[base];
            const ushort_t* pk = (const ushort_t*)&rk;
            const ushort_t* pv = (const ushort_t*)&rv;
            #pragma unroll
            for (int j = 0; j < 8; ++j) {
                Kl[r][c8 + j] = bf2f(pk[j]);
                Vl[r][c8 + j] = bf2f(pv[j]);
            }
        }
        if (tid < KT) {
            kx[tid] = sx[b * kL + k0 + tid];
            ky[tid] = sy[b * kL + k0 + tid];
        }
        __syncthreads();

        float s[4] = {};
        #pragma unroll
        for (int d4 = 0; d4 < 16; ++d4) {
            const float4 qv = *(const float4*)&Ql[ty][d4 * 4];
            #pragma unroll
            for (int jj = 0; jj < 4; ++jj) {
                const float4 kv = *(const float4*)&Kl[tx + 8 * jj][d4 * 4];
                s[jj] = fmaf(qv.x, kv.x, s[jj]);
                s[jj] = fmaf(qv.y, kv.y, s[jj]);
                s[jj] = fmaf(qv.z, kv.z, s[jj]);
                s[jj] = fmaf(qv.w, kv.w, s[jj]);
            }
        }

        float rxv[4], ryv[4];
        const float qxv = qx[ty], qyv = qy[ty];
        #pragma unroll
        for (int jj = 0; jj < 4; ++jj) {
            const int j = tx + 8 * jj;
            float dx = qxv - kx[j];
            float dy = qyv - ky[j];
            dx = fminf(fmaxf(dx, -1000.f), 1000.f);
            dy = fminf(fmaxf(dy, -1000.f), 1000.f);
            rxv[jj] = dx * 1e-3f;
            ryv[jj] = dy * 1e-3f;
        }
        #pragma unroll
        for (int u = 0; u < kPH; ++u) {
            const float a = p1a[u], bb = p1b[u], c = pc1[u], w = p2c[u];
            #pragma unroll
            for (int jj = 0; jj < 4; ++jj) {
                float t = fmaf(rxv[jj], a, fmaf(ryv[jj], bb, c));
                t = fmaxf(t, 0.f);
                s[jj] = fmaf(t, w, s[jj]);
            }
        }
        #pragma unroll
        for (int jj = 0; jj < 4; ++jj) s[jj] += pb2h;

        float tmax = fmaxf(fmaxf(s[0], s[1]), fmaxf(s[2], s[3]));
        tmax = fmaxf(tmax, __shfl_xor(tmax, 1, 8));
        tmax = fmaxf(tmax, __shfl_xor(tmax, 2, 8));
        tmax = fmaxf(tmax, __shfl_xor(tmax, 4, 8));
        const float mnew  = fmaxf(m_run, tmax);
        const float alpha = __expf(m_run - mnew);
        float lsum = 0.f;
        #pragma unroll
        for (int jj = 0; jj < 4; ++jj) {
            const float p = __expf(s[jj] - mnew);
            lsum += p;
            Sp[ty][tx + 8 * jj] = p;
        }
        lsum += __shfl_xor(lsum, 1, 8);
        lsum += __shfl_xor(lsum, 2, 8);
        lsum += __shfl_xor(lsum, 4, 8);
        l_run = l_run * alpha + lsum;
        m_run = mnew;
        #pragma unroll
        for (int c = 0; c < 8; ++c) accO[c] *= alpha;
        __syncthreads();

        #pragma unroll
        for (int j = 0; j < KT; ++j) {
            const float pj = Sp[ty][j];
            const float4 v0 = *(const float4*)&Vl[j][tx * 8];
            const float4 v1 = *(const float4*)&Vl[j][tx * 8 + 4];
            accO[0] = fmaf(pj, v0.x, accO[0]);
            accO[1] = fmaf(pj, v0.y, accO[1]);
            accO[2] = fmaf(pj, v0.z, accO[2]);
            accO[3] = fmaf(pj, v0.w, accO[3]);
            accO[4] = fmaf(pj, v1.x, accO[4]);
            accO[5] = fmaf(pj, v1.y, accO[5]);
            accO[6] = fmaf(pj, v1.z, accO[6]);
            accO[7] = fmaf(pj, v1.w, accO[7]);
        }
    }

    const float inv = 1.0f / l_run;
    ushort_t ov[8];
    #pragma unroll
    for (int c = 0; c < 8; ++c) ov[c] = f2bf(accO[c] * inv);
    *(uint4*)&og[(size_t)(b * kL + q0 + ty) * kD + h * kDK + tx * 8] = *(const uint4*)ov;
}

// ---------------------------------------------------------------------------
// Residual + LayerNorm, optional dual bf16 output
// ---------------------------------------------------------------------------
template<int DUAL>
__global__ __launch_bounds__(256)
void ln_kernel(const float* __restrict__ a, const float* __restrict__ r,
               const float* __restrict__ g, const float* __restrict__ be,
               float* __restrict__ out, ushort_t* __restrict__ out_bf)
{
    const int row = blockIdx.x;
    const int tid = threadIdx.x;
    const float* pa = a + (size_t)row * kD;
    const float* pr = r + (size_t)row * kD;

    float v[3];
    float s = 0.f, sq = 0.f;
    #pragma unroll
    for (int i = 0; i < 3; ++i) {
        const int d = tid + i * 256;
        v[i] = pa[d] + pr[d];
        s  += v[i];
        sq += v[i] * v[i];
    }
    #pragma unroll
    for (int off = 32; off > 0; off >>= 1) {
        s  += __shfl_down(s, off);
        sq += __shfl_down(sq, off);
    }
    __shared__ float bs[4], bq[4];
    if ((tid & 63) == 0) { bs[tid >> 6] = s; bq[tid >> 6] = sq; }
    __syncthreads();
    const float ts = bs[0] + bs[1] + bs[2] + bs[3];
    const float tq = bq[0] + bq[1] + bq[2] + bq[3];
    const float invn = 1.0f / (float)kD;
    const float mean = ts * invn;
    const float var  = tq * invn - mean * mean;
    const float rstd = rsqrtf(var + kEPS);

    float* po = out + (size_t)row * kD;
    #pragma unroll
    for (int i = 0; i < 3; ++i) {
        const int d = tid + i * 256;
        const float o = (v[i] - mean) * rstd * g[d] + be[d];
        po[d] = o;
        if (DUAL) out_bf[(size_t)row * kD + d] = f2bf(o);
    }
}

// ---------------------------------------------------------------------------
extern "C" void kernel_launch(void* const* d_in, const int* in_sizes, int n_in,
                              void* d_out, int out_size, void* d_ws, size_t ws_size,
                              hipStream_t stream)
{
    const float* src = (const float*)d_in[0];
    const float* sx  = (const float*)d_in[1];
    const float* sy  = (const float*)d_in[2];
    const float* Wq  = (const float*)d_in[3];  const float* bq  = (const float*)d_in[4];
    const float* Wk  = (const float*)d_in[5];  const float* bk  = (const float*)d_in[6];
    const float* Wv  = (const float*)d_in[7];  const float* bv  = (const float*)d_in[8];
    const float* Wo  = (const float*)d_in[9];  const float* bo  = (const float*)d_in[10];
    const float* P1  = (const float*)d_in[11]; const float* pb1 = (const float*)d_in[12];
    const float* P2  = (const float*)d_in[13]; const float* pb2 = (const float*)d_in[14];
    const float* W1  = (const float*)d_in[15]; const float* b1  = (const float*)d_in[16];
    const float* W2  = (const float*)d_in[17]; const float* b2  = (const float*)d_in[18];
    const float* g1  = (const float*)d_in[19]; const float* be1 = (const float*)d_in[20];
    const float* g2  = (const float*)d_in[21]; const float* be2 = (const float*)d_in[22];

    // ---- workspace arena (bytes) ----
    char* ws = (char*)d_ws;
    constexpr size_t W768  = 768u * 768u;       // 589824
    constexpr size_t W3072 = 768u * 3072u;      // 2359296
    constexpr size_t NTOK  = (size_t)kRows * kD;  // 1572864

    ushort_t* wqT = (ushort_t*)ws;
    ushort_t* wkT = wqT + W768;
    ushort_t* wvT = wkT + W768;
    ushort_t* woT = wvT + W768;
    ushort_t* w1T = woT + W768;
    ushort_t* w2T = w1T + W3072;
    ushort_t* qb  = w2T + W3072;        // bf16 q           (3.15 MB)
    ushort_t* kb  = qb + NTOK;          // bf16 k
    ushort_t* vb  = kb + NTOK;          // bf16 v
    ushort_t* sb  = vb + NTOK;          // src_bf, later ob_bf
    float*    s2  = (float*)(sb + NTOK);   // src2 fp32      (6.29 MB)
    float*    xb  = s2 + NTOK;             // x fp32         (6.29 MB)
    ushort_t* xbf   = qb;               // bf16 x (q dead after attn)
    ushort_t* h1bf  = kb;               // FFN1 out bf16: spans kb|vb|sb|part of s2 (all dead)
    float*    ff2   = (float*)d_out;    // FFN2 out, LN2 in-place

    const dim3 blk(256);

    // 1. weight transpose+convert (all 6), 2. src -> bf16
    WtArgs wa;
    wa.d[0] = { Wq, wqT, kD,  kD  };
    wa.d[1] = { Wk, wkT, kD,  kD  };
    wa.d[2] = { Wv, wvT, kD,  kD  };
    wa.d[3] = { Wo, woT, kD,  kD  };
    wa.d[4] = { W1, w1T, kD,  kFF };
    wa.d[5] = { W2, w2T, kFF, kD  };
    wt_kernel<<<dim3(576, 1, 6), blk, 0, stream>>>(wa);
    cvt_kernel<<<dim3(NTOK / 4 / 256), blk, 0, stream>>>(src, sb, NTOK / 4);

    // 3. fused QKV projection (bf16 out)
    gemm_qkv_kernel<<<dim3(kD / 128, kRows / 128, 3), blk, 0, stream>>>(
        sb, wqT, wkT, wvT, bq, bk, bv, qb, kb, vb);

    // 4. attention (bf16 in, bf16 out into sb)
    attn_kernel<<<dim3(2 * kNH, kL / 32), blk, 0, stream>>>(
        qb, kb, vb, sx, sy, P1, pb1, P2, pb2, sb);

    // 5. out-projection (fp32 out)
    gemm_kernel<0, 0><<<dim3(kD / 128, kRows / 128), blk, 0, stream>>>(
        sb, woT, bo, s2, kD, kD);

    // 6. LN1: x = LN(src + src2), fp32 + bf16
    ln_kernel<1><<<dim3(kRows), blk, 0, stream>>>(src, s2, g1, be1, xb, xbf);

    // 7. FFN1: relu(x @ W1 + b1) -> bf16
    gemm_kernel<1, 1><<<dim3(kFF / 128, kRows / 128), blk, 0, stream>>>(
        xbf, w1T, b1, h1bf, kFF, kD);

    // 8. FFN2 -> d_out (fp32)
    gemm_kernel<0, 0><<<dim3(kD / 128, kRows / 128), blk, 0, stream>>>(
        h1bf, w2T, b2, ff2, kD, kFF);

    // 9. LN2 in-place on d_out
    ln_kernel<0><<<dim3(kRows), blk, 0, stream>>>(xb, ff2, g2, be2, (float*)d_out, nullptr);
}

// Round 3
// 354.519 us; speedup vs baseline: 2.3628x; 1.3180x over previous
//
#include <hip/hip_runtime.h>
#include <math.h>

typedef unsigned short ushort_t;
typedef __attribute__((ext_vector_type(8))) short bf16x8;
typedef __attribute__((ext_vector_type(4))) float f32x4;

constexpr int kD      = 768;
constexpr int kNH     = 12;
constexpr int kDK     = 64;
constexpr int kFF     = 3072;
constexpr int kL      = 1024;
constexpr int kRows   = 2048;     // B * L
constexpr float kEPS  = 1e-5f;

__device__ __forceinline__ ushort_t f2bf(float f) {
    union { float f; unsigned u; } v; v.f = f;
    unsigned r = (v.u + 0x7fffu + ((v.u >> 16) & 1u)) >> 16;
    return (ushort_t)r;
}
__device__ __forceinline__ float bf2f(ushort_t u) {
    union { unsigned u; float f; } v; v.u = ((unsigned)u) << 16; return v.f;
}

#define GL_LDS(gp, lp) __builtin_amdgcn_global_load_lds( \
    (const __attribute__((address_space(1))) void*)(gp), \
    (__attribute__((address_space(3))) void*)(lp), 16, 0, 0)

// ---------------------------------------------------------------------------
// bf16 MFMA GEMM (m97 structure): 128x128 tile, BK=32, 4 waves.
// ---------------------------------------------------------------------------
template<int RELU, int OUTBF>
__device__ __forceinline__ void gemm_body(const ushort_t* __restrict__ A,
                                          const ushort_t* __restrict__ WT,
                                          const float* __restrict__ bias,
                                          void* __restrict__ Cout,
                                          int N, int K, int row0, int col0)
{
    __shared__ ushort_t lds[8192];
    ushort_t* As = lds;
    ushort_t* Bs = lds + 4096;

    const int tid  = threadIdx.x;
    const int lane = tid & 63;
    const int wave = tid >> 6;
    const int wrow = (wave & 1) * 64;
    const int wcol = (wave >> 1) * 64;

    const int srow = wave * 16 + (lane >> 2);
    const int sk   = (lane & 3) * 8;
    const ushort_t* ga0 = A  + (size_t)(row0 + srow)      * K + sk;
    const ushort_t* ga1 = A  + (size_t)(row0 + srow + 64) * K + sk;
    const ushort_t* gb0 = WT + (size_t)(col0 + srow)      * K + sk;
    const ushort_t* gb1 = WT + (size_t)(col0 + srow + 64) * K + sk;
    ushort_t* la0 = As + wave * 512;
    ushort_t* la1 = As + 2048 + wave * 512;
    ushort_t* lb0 = Bs + wave * 512;
    ushort_t* lb1 = Bs + 2048 + wave * 512;

    const int fl = lane & 15, fq = lane >> 4;
    const ushort_t* fa[4];
    const ushort_t* fb[4];
    #pragma unroll
    for (int i = 0; i < 4; ++i) {
        fa[i] = As + (wrow + i * 16 + fl) * 32 + fq * 8;
        fb[i] = Bs + (wcol + i * 16 + fl) * 32 + fq * 8;
    }

    f32x4 acc[4][4] = {};

    for (int k0 = 0; k0 < K; k0 += 32) {
        __syncthreads();
        GL_LDS(ga0 + k0, la0);
        GL_LDS(ga1 + k0, la1);
        GL_LDS(gb0 + k0, lb0);
        GL_LDS(gb1 + k0, lb1);
        __syncthreads();

        bf16x8 av[4], bv[4];
        #pragma unroll
        for (int i = 0; i < 4; ++i) {
            av[i] = *(const bf16x8*)fa[i];
            bv[i] = *(const bf16x8*)fb[i];
        }
        #pragma unroll
        for (int mi = 0; mi < 4; ++mi)
            #pragma unroll
            for (int ni = 0; ni < 4; ++ni)
                acc[mi][ni] = __builtin_amdgcn_mfma_f32_16x16x32_bf16(
                    av[mi], bv[ni], acc[mi][ni], 0, 0, 0);
    }

    #pragma unroll
    for (int mi = 0; mi < 4; ++mi) {
        const int m = wrow + mi * 16 + fq * 4;
        #pragma unroll
        for (int ni = 0; ni < 4; ++ni) {
            const int n = wcol + ni * 16 + fl;
            const float bb = bias[col0 + n];
            #pragma unroll
            for (int r = 0; r < 4; ++r) {
                float v = acc[mi][ni][r] + bb;
                if (RELU) v = fmaxf(v, 0.f);
                const size_t idx = (size_t)(row0 + m + r) * N + col0 + n;
                if (OUTBF) ((ushort_t*)Cout)[idx] = f2bf(v);
                else       ((float*)Cout)[idx]    = v;
            }
        }
    }
}

template<int RELU, int OUTBF>
__global__ __launch_bounds__(256)
void gemm_kernel(const ushort_t* __restrict__ A, const ushort_t* __restrict__ WT,
                 const float* __restrict__ bias, void* __restrict__ Cout,
                 int N, int K)
{
    gemm_body<RELU, OUTBF>(A, WT, bias, Cout, N, K, blockIdx.y * 128, blockIdx.x * 128);
}

__global__ __launch_bounds__(256)
void gemm_qkv_kernel(const ushort_t* __restrict__ A,
                     const ushort_t* wq, const ushort_t* wk, const ushort_t* wv,
                     const float* bq, const float* bk, const float* bv,
                     ushort_t* q, ushort_t* k, ushort_t* v)
{
    const ushort_t* WT; const float* bias; ushort_t* out;
    if (blockIdx.z == 0)      { WT = wq; bias = bq; out = q; }
    else if (blockIdx.z == 1) { WT = wk; bias = bk; out = k; }
    else                      { WT = wv; bias = bv; out = v; }
    gemm_body<0, 1>(A, WT, bias, out, kD, kD, blockIdx.y * 128, blockIdx.x * 128);
}

// ---------------------------------------------------------------------------
// Weight transpose + fp32->bf16:  W[K][N] -> WT[N][K] bf16.
// ---------------------------------------------------------------------------
struct WtDesc { const float* src; ushort_t* dst; int K; int N; };
struct WtArgs { WtDesc d[3]; };

__global__ __launch_bounds__(256)
void wt_kernel(WtArgs args)
{
    const WtDesc w = args.d[blockIdx.z];
    const int ktiles = w.K >> 6;
    const int kt = (blockIdx.x % ktiles) * 64;
    const int nt = (blockIdx.x / ktiles) * 64;
    if (nt >= w.N) return;

    __shared__ float T[64][65];
    const int tid = threadIdx.x;
    #pragma unroll
    for (int i = 0; i < 4; ++i) {
        const int e = tid + i * 256;
        const int r = e >> 4;
        const int c = (e & 15) * 4;
        const float4 f = *(const float4*)&w.src[(size_t)(kt + r) * w.N + nt + c];
        T[c + 0][r] = f.x; T[c + 1][r] = f.y; T[c + 2][r] = f.z; T[c + 3][r] = f.w;
    }
    __syncthreads();
    #pragma unroll
    for (int i = 0; i < 4; ++i) {
        const int e = tid + i * 256;
        const int n = e >> 4;
        const int kc = (e & 15) * 4;
        ushort4 o;
        o.x = f2bf(T[n][kc + 0]); o.y = f2bf(T[n][kc + 1]);
        o.z = f2bf(T[n][kc + 2]); o.w = f2bf(T[n][kc + 3]);
        *(ushort4*)&w.dst[(size_t)(nt + n) * w.K + kt + kc] = o;
    }
}

// fp32 -> bf16 elementwise
__global__ __launch_bounds__(256)
void cvt_kernel(const float* __restrict__ in, ushort_t* __restrict__ out, int n4)
{
    const int i = blockIdx.x * 256 + threadIdx.x;
    if (i < n4) {
        const float4 f = ((const float4*)in)[i];
        ushort4 o;
        o.x = f2bf(f.x); o.y = f2bf(f.y); o.z = f2bf(f.z); o.w = f2bf(f.w);
        ((ushort4*)out)[i] = o;
    }
}

// ---------------------------------------------------------------------------
// V transpose per head: vb[b*L+j][h*64+d] -> vt[(b*12+h)*64+d][j]
// grid (24, 16), block 256: tile 64 j x 64 d
// ---------------------------------------------------------------------------
__global__ __launch_bounds__(256)
void vtrans_kernel(const ushort_t* __restrict__ vb, ushort_t* __restrict__ vt)
{
    const int bh = blockIdx.x;
    const int b = bh / kNH, h = bh - b * kNH;
    const int j0 = blockIdx.y * 64;
    __shared__ ushort_t T[64][72];   // [d][j]

    const int tid = threadIdx.x;
    {   // load: jr = tid&63, c0 = (tid>>6)*16
        const int jr = tid & 63;
        const int c0 = (tid >> 6) * 16;
        const ushort_t* sp = vb + (size_t)(b * kL + j0 + jr) * kD + h * kDK + c0;
        uint4 u0 = *(const uint4*)sp;
        uint4 u1 = *(const uint4*)(sp + 8);
        const ushort_t* e0 = (const ushort_t*)&u0;
        const ushort_t* e1 = (const ushort_t*)&u1;
        #pragma unroll
        for (int jj = 0; jj < 8; ++jj) {
            T[c0 + jj][jr]     = e0[jj];
            T[c0 + 8 + jj][jr] = e1[jj];
        }
    }
    __syncthreads();
    {   // store: dr = tid>>2, jc = (tid&3)*16
        const int dr = tid >> 2;
        const int jc = (tid & 3) * 16;
        ushort_t* dp = vt + (size_t)(bh * 64 + dr) * kL + j0 + jc;
        *(uint4*)dp       = *(const uint4*)&T[dr][jc];
        *(uint4*)(dp + 8) = *(const uint4*)&T[dr][jc + 8];
    }
}

// ---------------------------------------------------------------------------
// Relative-position bias, all heads at once:
// bias_bf[(bh)*L + i][j] = bf16( relu([rx,ry] @ P1 + pb1) @ P2[:,h] + pb2[h] )
// grid 8192, block 256: bid -> (b, i, j-chunk)
// ---------------------------------------------------------------------------
__global__ __launch_bounds__(256)
void bias_kernel(const float* __restrict__ sx, const float* __restrict__ sy,
                 const float* __restrict__ P1, const float* __restrict__ pb1,
                 const float* __restrict__ P2, const float* __restrict__ pb2,
                 ushort_t* __restrict__ biasb)
{
    const int bid = blockIdx.x;
    const int b = bid >> 12;
    const int i = (bid >> 2) & 1023;
    const int j = (bid & 3) * 256 + threadIdx.x;
    const int tid = threadIdx.x;

    __shared__ float A1[32], B1[32], C1[32], W2l[384], pb2l[12];
    if (tid < 32) { A1[tid] = P1[tid]; B1[tid] = P1[32 + tid]; C1[tid] = pb1[tid]; }
    if (tid < 12) pb2l[tid] = pb2[tid];
    for (int e = tid; e < 384; e += 256) W2l[e] = P2[e];
    __syncthreads();

    const float xi = sx[b * kL + i], yi = sy[b * kL + i];
    float rx = xi - sx[b * kL + j];
    float ry = yi - sy[b * kL + j];
    rx = fminf(fmaxf(rx, -1000.f), 1000.f) * 1e-3f;
    ry = fminf(fmaxf(ry, -1000.f), 1000.f) * 1e-3f;

    float acc[12] = {};
    #pragma unroll
    for (int u = 0; u < 32; ++u) {
        float t = fmaf(rx, A1[u], fmaf(ry, B1[u], C1[u]));
        t = fmaxf(t, 0.f);
        #pragma unroll
        for (int h = 0; h < 12; ++h)
            acc[h] = fmaf(t, W2l[u * 12 + h], acc[h]);
    }
    #pragma unroll
    for (int h = 0; h < 12; ++h)
        biasb[((size_t)(b * kNH + h) * kL + i) * kL + j] = f2bf(acc[h] + pb2l[h]);
}

// ---------------------------------------------------------------------------
// MFMA flash attention. 1 wave/block, 16 q-rows, K-tiles of 64.
// grid (24, 64).  Q/K B-frags from global; V from vt (transposed); bias from
// biasb.  P round-trips through per-wave LDS.  O in C-layout accumulators.
// ---------------------------------------------------------------------------
__global__ __launch_bounds__(64)
void attn_kernel(const ushort_t* __restrict__ qg, const ushort_t* __restrict__ kg,
                 const ushort_t* __restrict__ vt, const ushort_t* __restrict__ biasb,
                 ushort_t* __restrict__ og)
{
    const int bh = blockIdx.x;
    const int b  = bh / kNH, h = bh - b * kNH;
    const int q0 = blockIdx.y * 16;
    const int lane = threadIdx.x;
    const int fl = lane & 15, fq = lane >> 4;

    __shared__ ushort_t Sp[16][72];   // P: [qrow][jcol], 144B rows (16B-aligned)

    // Q A-fragments (fixed over K-loop)
    const size_t qoff = (size_t)(b * kL + q0 + fl) * kD + h * kDK + fq * 8;
    const bf16x8 aq0 = *(const bf16x8*)(qg + qoff);
    const bf16x8 aq1 = *(const bf16x8*)(qg + qoff + 32);

    const ushort_t* kbase = kg + (size_t)(b * kL) * kD + h * kDK;
    const ushort_t* vbase = vt + (size_t)(bh * 64) * kL;
    const ushort_t* bbase = biasb + ((size_t)bh * kL + q0) * kL;

    f32x4 accO[4] = {};
    float m_run[4] = {-INFINITY, -INFINITY, -INFINITY, -INFINITY};
    float l_run[4] = {};

    for (int k0 = 0; k0 < kL; k0 += 64) {
        // bias loads first (independent of MFMA chain)
        float bvals[4][4];
        #pragma unroll
        for (int r = 0; r < 4; ++r)
            #pragma unroll
            for (int n = 0; n < 4; ++n)
                bvals[n][r] = bf2f(bbase[(size_t)(fq * 4 + r) * kL + k0 + n * 16 + fl]);

        // S = Q K^T (4 col-tiles x 2 k-chunks)
        f32x4 S[4] = {};
        #pragma unroll
        for (int n = 0; n < 4; ++n) {
            const ushort_t* kr = kbase + (size_t)(k0 + n * 16 + fl) * kD + fq * 8;
            const bf16x8 bk0 = *(const bf16x8*)kr;
            const bf16x8 bk1 = *(const bf16x8*)(kr + 32);
            S[n] = __builtin_amdgcn_mfma_f32_16x16x32_bf16(aq0, bk0, S[n], 0, 0, 0);
            S[n] = __builtin_amdgcn_mfma_f32_16x16x32_bf16(aq1, bk1, S[n], 0, 0, 0);
        }
        #pragma unroll
        for (int n = 0; n < 4; ++n)
            #pragma unroll
            for (int r = 0; r < 4; ++r)
                S[n][r] = fmaf(S[n][r], 0.125f, bvals[n][r]);

        // online softmax per row r (rows quad*4+r, replicated across 16 lanes)
        #pragma unroll
        for (int r = 0; r < 4; ++r) {
            float mx = fmaxf(fmaxf(S[0][r], S[1][r]), fmaxf(S[2][r], S[3][r]));
            mx = fmaxf(mx, __shfl_xor(mx, 1, 16));
            mx = fmaxf(mx, __shfl_xor(mx, 2, 16));
            mx = fmaxf(mx, __shfl_xor(mx, 4, 16));
            mx = fmaxf(mx, __shfl_xor(mx, 8, 16));
            const float mnew  = fmaxf(m_run[r], mx);
            const float alpha = __expf(m_run[r] - mnew);
            float ls = 0.f;
            #pragma unroll
            for (int n = 0; n < 4; ++n) {
                const float e = __expf(S[n][r] - mnew);
                S[n][r] = e;
                ls += e;
            }
            ls += __shfl_xor(ls, 1, 16);
            ls += __shfl_xor(ls, 2, 16);
            ls += __shfl_xor(ls, 4, 16);
            ls += __shfl_xor(ls, 8, 16);
            l_run[r] = l_run[r] * alpha + ls;
            m_run[r] = mnew;
            #pragma unroll
            for (int n = 0; n < 4; ++n) accO[n][r] *= alpha;
        }

        // P -> LDS (C-layout positions)
        #pragma unroll
        for (int n = 0; n < 4; ++n)
            #pragma unroll
            for (int r = 0; r < 4; ++r)
                Sp[fq * 4 + r][n * 16 + fl] = f2bf(S[n][r]);
        __syncthreads();   // single wave: cheap; orders LDS write->read

        // O += P V   (A from Sp, B from vt)
        const bf16x8 ap0 = *(const bf16x8*)&Sp[fl][fq * 8];
        const bf16x8 ap1 = *(const bf16x8*)&Sp[fl][32 + fq * 8];
        #pragma unroll
        for (int n = 0; n < 4; ++n) {
            const ushort_t* vr = vbase + (size_t)(n * 16 + fl) * kL + k0 + fq * 8;
            const bf16x8 bv0 = *(const bf16x8*)vr;
            const bf16x8 bv1 = *(const bf16x8*)(vr + 32);
            accO[n] = __builtin_amdgcn_mfma_f32_16x16x32_bf16(ap0, bv0, accO[n], 0, 0, 0);
            accO[n] = __builtin_amdgcn_mfma_f32_16x16x32_bf16(ap1, bv1, accO[n], 0, 0, 0);
        }
        __syncthreads();   // Sp WAR before next tile
    }

    float inv[4];
    #pragma unroll
    for (int r = 0; r < 4; ++r) inv[r] = 1.0f / l_run[r];
    #pragma unroll
    for (int n = 0; n < 4; ++n)
        #pragma unroll
        for (int r = 0; r < 4; ++r)
            og[(size_t)(b * kL + q0 + fq * 4 + r) * kD + h * kDK + n * 16 + fl] =
                f2bf(accO[n][r] * inv[r]);
}

// ---------------------------------------------------------------------------
// Residual + LayerNorm, optional dual bf16 output
// ---------------------------------------------------------------------------
template<int DUAL>
__global__ __launch_bounds__(256)
void ln_kernel(const float* __restrict__ a, const float* __restrict__ r,
               const float* __restrict__ g, const float* __restrict__ be,
               float* __restrict__ out, ushort_t* __restrict__ out_bf)
{
    const int row = blockIdx.x;
    const int tid = threadIdx.x;
    const float* pa = a + (size_t)row * kD;
    const float* pr = r + (size_t)row * kD;

    float v[3];
    float s = 0.f, sq = 0.f;
    #pragma unroll
    for (int i = 0; i < 3; ++i) {
        const int d = tid + i * 256;
        v[i] = pa[d] + pr[d];
        s  += v[i];
        sq += v[i] * v[i];
    }
    #pragma unroll
    for (int off = 32; off > 0; off >>= 1) {
        s  += __shfl_down(s, off);
        sq += __shfl_down(sq, off);
    }
    __shared__ float bs[4], bq[4];
    if ((tid & 63) == 0) { bs[tid >> 6] = s; bq[tid >> 6] = sq; }
    __syncthreads();
    const float ts = bs[0] + bs[1] + bs[2] + bs[3];
    const float tq = bq[0] + bq[1] + bq[2] + bq[3];
    const float invn = 1.0f / (float)kD;
    const float mean = ts * invn;
    const float var  = tq * invn - mean * mean;
    const float rstd = rsqrtf(var + kEPS);

    float* po = out + (size_t)row * kD;
    #pragma unroll
    for (int i = 0; i < 3; ++i) {
        const int d = tid + i * 256;
        const float o = (v[i] - mean) * rstd * g[d] + be[d];
        po[d] = o;
        if (DUAL) out_bf[(size_t)row * kD + d] = f2bf(o);
    }
}

// ---------------------------------------------------------------------------
extern "C" void kernel_launch(void* const* d_in, const int* in_sizes, int n_in,
                              void* d_out, int out_size, void* d_ws, size_t ws_size,
                              hipStream_t stream)
{
    const float* src = (const float*)d_in[0];
    const float* sx  = (const float*)d_in[1];
    const float* sy  = (const float*)d_in[2];
    const float* Wq  = (const float*)d_in[3];  const float* bq  = (const float*)d_in[4];
    const float* Wk  = (const float*)d_in[5];  const float* bk  = (const float*)d_in[6];
    const float* Wv  = (const float*)d_in[7];  const float* bv  = (const float*)d_in[8];
    const float* Wo  = (const float*)d_in[9];  const float* bo  = (const float*)d_in[10];
    const float* P1  = (const float*)d_in[11]; const float* pb1 = (const float*)d_in[12];
    const float* P2  = (const float*)d_in[13]; const float* pb2 = (const float*)d_in[14];
    const float* W1  = (const float*)d_in[15]; const float* b1  = (const float*)d_in[16];
    const float* W2  = (const float*)d_in[17]; const float* b2  = (const float*)d_in[18];
    const float* g1  = (const float*)d_in[19]; const float* be1 = (const float*)d_in[20];
    const float* g2  = (const float*)d_in[21]; const float* be2 = (const float*)d_in[22];

    // ---- workspace arena (ushort units) ----
    constexpr size_t W768  = 768u * 768u;           // 589824
    constexpr size_t W3072 = 768u * 3072u;          // 2359296
    constexpr size_t NTOK  = (size_t)kRows * kD;    // 1572864
    constexpr size_t NBIAS = (size_t)2 * kNH * kL * kL;  // 25165824

    ushort_t* wsu = (ushort_t*)d_ws;
    ushort_t* wqT = wsu;                 // live: whole run
    ushort_t* wkT = wqT + W768;
    ushort_t* wvT = wkT + W768;
    ushort_t* qb  = wvT + W768;          // bf16 q/k/v
    ushort_t* kb  = qb + NTOK;
    ushort_t* vb  = kb + NTOK;
    ushort_t* sb  = vb + NTOK;           // src_bf -> attn out
    ushort_t* vtb = sb + NTOK;           // V transposed per head
    ushort_t* biasb = vtb + NTOK;        // 50 MB bias; aliased after attention:
    ushort_t* woT  = biasb;                            // |- Wo^T
    ushort_t* w1T  = woT + W768;                       // |- W1^T
    ushort_t* w2T  = w1T + W3072;                      // |- W2^T
    float*    s2   = (float*)(w2T + W3072);            // |- attn out-proj (fp32)
    float*    xb   = s2 + NTOK;                        // |- x (fp32)
    ushort_t* h1bf = (ushort_t*)(xb + NTOK);           // |- FFN hidden (bf16)
    ushort_t* xbf  = qb;                 // bf16 x (qb dead after attn)

    const dim3 blk(256);

    // 1. early weight transposes (q,k,v) + src->bf16 + bias table
    WtArgs wa_early;
    wa_early.d[0] = { Wq, wqT, kD, kD };
    wa_early.d[1] = { Wk, wkT, kD, kD };
    wa_early.d[2] = { Wv, wvT, kD, kD };
    wt_kernel<<<dim3(144, 1, 3), blk, 0, stream>>>(wa_early);
    cvt_kernel<<<dim3((int)(NTOK / 4 / 256)), blk, 0, stream>>>(src, sb, (int)(NTOK / 4));
    bias_kernel<<<dim3(8192), blk, 0, stream>>>(sx, sy, P1, pb1, P2, pb2, biasb);

    // 2. QKV projection
    gemm_qkv_kernel<<<dim3(kD / 128, kRows / 128, 3), blk, 0, stream>>>(
        sb, wqT, wkT, wvT, bq, bk, bv, qb, kb, vb);

    // 3. V transpose per head
    vtrans_kernel<<<dim3(2 * kNH, kL / 64), blk, 0, stream>>>(vb, vtb);

    // 4. MFMA flash attention (writes bf16 into sb)
    attn_kernel<<<dim3(2 * kNH, kL / 16), dim3(64), 0, stream>>>(qb, kb, vtb, biasb, sb);

    // 5. late weight transposes (o, ffn) into the now-dead bias region
    WtArgs wa_late;
    wa_late.d[0] = { Wo, woT, kD,  kD  };
    wa_late.d[1] = { W1, w1T, kD,  kFF };
    wa_late.d[2] = { W2, w2T, kFF, kD  };
    wt_kernel<<<dim3(576, 1, 3), blk, 0, stream>>>(wa_late);

    // 6. out-projection (fp32 out)
    gemm_kernel<0, 0><<<dim3(kD / 128, kRows / 128), blk, 0, stream>>>(
        sb, woT, bo, s2, kD, kD);

    // 7. LN1: x = LN(src + s2), fp32 + bf16
    ln_kernel<1><<<dim3(kRows), blk, 0, stream>>>(src, s2, g1, be1, xb, xbf);

    // 8. FFN1: relu(x @ W1 + b1) -> bf16
    gemm_kernel<1, 1><<<dim3(kFF / 128, kRows / 128), blk, 0, stream>>>(
        xbf, w1T, b1, h1bf, kFF, kD);

    // 9. FFN2 -> d_out (fp32)
    gemm_kernel<0, 0><<<dim3(kD / 128, kRows / 128), blk, 0, stream>>>(
        h1bf, w2T, b2, (float*)d_out, kD, kFF);

    // 10. LN2 in-place on d_out
    ln_kernel<0><<<dim3(kRows), blk, 0, stream>>>(xb, (float*)d_out, g2, be2,
                                                  (float*)d_out, nullptr);
}

// Round 4
// 310.268 us; speedup vs baseline: 2.6998x; 1.1426x over previous
//
#include <hip/hip_runtime.h>
#include <math.h>

typedef unsigned short ushort_t;
typedef __attribute__((ext_vector_type(8))) short bf16x8;
typedef __attribute__((ext_vector_type(4))) float f32x4;

constexpr int kD      = 768;
constexpr int kNH     = 12;
constexpr int kDK     = 64;
constexpr int kFF     = 3072;
constexpr int kL      = 1024;
constexpr int kRows   = 2048;     // B * L
constexpr float kEPS  = 1e-5f;

__device__ __forceinline__ ushort_t f2bf(float f) {
    union { float f; unsigned u; } v; v.f = f;
    unsigned r = (v.u + 0x7fffu + ((v.u >> 16) & 1u)) >> 16;
    return (ushort_t)r;
}
__device__ __forceinline__ float bf2f(ushort_t u) {
    union { unsigned u; float f; } v; v.u = ((unsigned)u) << 16; return v.f;
}

#define GL_LDS(gp, lp) __builtin_amdgcn_global_load_lds( \
    (const __attribute__((address_space(1))) void*)(gp), \
    (__attribute__((address_space(3))) void*)(lp), 16, 0, 0)

// ---------------------------------------------------------------------------
// bf16 MFMA GEMM (m97 structure): 128x128 tile, BK=32, 4 waves.
// Computes C[row0:+128, col0:+128] = A[:, kbeg:kend] @ WT[:, kbeg:kend]^T
// ---------------------------------------------------------------------------
template<int RELU, int OUTBF, int ADDBIAS>
__device__ __forceinline__ void gemm_body(const ushort_t* __restrict__ A,
                                          const ushort_t* __restrict__ WT,
                                          const float* __restrict__ bias,
                                          void* __restrict__ Cout,
                                          int N, int K, int row0, int col0,
                                          int kbeg, int kend)
{
    __shared__ ushort_t lds[8192];
    ushort_t* As = lds;
    ushort_t* Bs = lds + 4096;

    const int tid  = threadIdx.x;
    const int lane = tid & 63;
    const int wave = tid >> 6;
    const int wrow = (wave & 1) * 64;
    const int wcol = (wave >> 1) * 64;

    const int srow = wave * 16 + (lane >> 2);
    const int sk   = (lane & 3) * 8;
    const ushort_t* ga0 = A  + (size_t)(row0 + srow)      * K + sk;
    const ushort_t* ga1 = A  + (size_t)(row0 + srow + 64) * K + sk;
    const ushort_t* gb0 = WT + (size_t)(col0 + srow)      * K + sk;
    const ushort_t* gb1 = WT + (size_t)(col0 + srow + 64) * K + sk;
    ushort_t* la0 = As + wave * 512;
    ushort_t* la1 = As + 2048 + wave * 512;
    ushort_t* lb0 = Bs + wave * 512;
    ushort_t* lb1 = Bs + 2048 + wave * 512;

    const int fl = lane & 15, fq = lane >> 4;
    const ushort_t* fa[4];
    const ushort_t* fb[4];
    #pragma unroll
    for (int i = 0; i < 4; ++i) {
        fa[i] = As + (wrow + i * 16 + fl) * 32 + fq * 8;
        fb[i] = Bs + (wcol + i * 16 + fl) * 32 + fq * 8;
    }

    f32x4 acc[4][4] = {};

    for (int k0 = kbeg; k0 < kend; k0 += 32) {
        __syncthreads();
        GL_LDS(ga0 + k0, la0);
        GL_LDS(ga1 + k0, la1);
        GL_LDS(gb0 + k0, lb0);
        GL_LDS(gb1 + k0, lb1);
        __syncthreads();

        bf16x8 av[4], bv[4];
        #pragma unroll
        for (int i = 0; i < 4; ++i) {
            av[i] = *(const bf16x8*)fa[i];
            bv[i] = *(const bf16x8*)fb[i];
        }
        #pragma unroll
        for (int mi = 0; mi < 4; ++mi)
            #pragma unroll
            for (int ni = 0; ni < 4; ++ni)
                acc[mi][ni] = __builtin_amdgcn_mfma_f32_16x16x32_bf16(
                    av[mi], bv[ni], acc[mi][ni], 0, 0, 0);
    }

    #pragma unroll
    for (int mi = 0; mi < 4; ++mi) {
        const int m = wrow + mi * 16 + fq * 4;
        #pragma unroll
        for (int ni = 0; ni < 4; ++ni) {
            const int n = wcol + ni * 16 + fl;
            const float bb = ADDBIAS ? bias[col0 + n] : 0.f;
            #pragma unroll
            for (int r = 0; r < 4; ++r) {
                float v = acc[mi][ni][r] + bb;
                if (RELU) v = fmaxf(v, 0.f);
                const size_t idx = (size_t)(row0 + m + r) * N + col0 + n;
                if (OUTBF) ((ushort_t*)Cout)[idx] = f2bf(v);
                else       ((float*)Cout)[idx]    = v;
            }
        }
    }
}

template<int RELU, int OUTBF>
__global__ __launch_bounds__(256)
void gemm_kernel(const ushort_t* __restrict__ A, const ushort_t* __restrict__ WT,
                 const float* __restrict__ bias, void* __restrict__ Cout,
                 int N, int K)
{
    gemm_body<RELU, OUTBF, 1>(A, WT, bias, Cout, N, K,
                              blockIdx.y * 128, blockIdx.x * 128, 0, K);
}

// split-K partial GEMM: parts[z] = A[:, z*kslice:+kslice] @ WT^T  (fp32, no bias)
__global__ __launch_bounds__(256)
void gemm_splitk_kernel(const ushort_t* __restrict__ A, const ushort_t* __restrict__ WT,
                        float* __restrict__ parts, int N, int K, int kslice)
{
    const int z = blockIdx.z;
    float* out = parts + (size_t)z * kRows * N;
    gemm_body<0, 0, 0>(A, WT, nullptr, out, N, K,
                       blockIdx.y * 128, blockIdx.x * 128, z * kslice, (z + 1) * kslice);
}

__global__ __launch_bounds__(256)
void gemm_qkv_kernel(const ushort_t* __restrict__ A,
                     const ushort_t* wq, const ushort_t* wk, const ushort_t* wv,
                     const float* bq, const float* bk, const float* bv,
                     ushort_t* q, ushort_t* k, ushort_t* v)
{
    const ushort_t* WT; const float* bias; ushort_t* out;
    if (blockIdx.z == 0)      { WT = wq; bias = bq; out = q; }
    else if (blockIdx.z == 1) { WT = wk; bias = bk; out = k; }
    else                      { WT = wv; bias = bv; out = v; }
    gemm_body<0, 1, 1>(A, WT, bias, out, kD, kD,
                       blockIdx.y * 128, blockIdx.x * 128, 0, kD);
}

// ---------------------------------------------------------------------------
// Weight transpose + fp32->bf16:  W[K][N] -> WT[N][K] bf16.
// ---------------------------------------------------------------------------
struct WtDesc { const float* src; ushort_t* dst; int K; int N; };
struct WtArgs { WtDesc d[3]; };

__global__ __launch_bounds__(256)
void wt_kernel(WtArgs args)
{
    const WtDesc w = args.d[blockIdx.z];
    const int ktiles = w.K >> 6;
    const int kt = (blockIdx.x % ktiles) * 64;
    const int nt = (blockIdx.x / ktiles) * 64;
    if (nt >= w.N) return;

    __shared__ float T[64][65];
    const int tid = threadIdx.x;
    #pragma unroll
    for (int i = 0; i < 4; ++i) {
        const int e = tid + i * 256;
        const int r = e >> 4;
        const int c = (e & 15) * 4;
        const float4 f = *(const float4*)&w.src[(size_t)(kt + r) * w.N + nt + c];
        T[c + 0][r] = f.x; T[c + 1][r] = f.y; T[c + 2][r] = f.z; T[c + 3][r] = f.w;
    }
    __syncthreads();
    #pragma unroll
    for (int i = 0; i < 4; ++i) {
        const int e = tid + i * 256;
        const int n = e >> 4;
        const int kc = (e & 15) * 4;
        ushort4 o;
        o.x = f2bf(T[n][kc + 0]); o.y = f2bf(T[n][kc + 1]);
        o.z = f2bf(T[n][kc + 2]); o.w = f2bf(T[n][kc + 3]);
        *(ushort4*)&w.dst[(size_t)(nt + n) * w.K + kt + kc] = o;
    }
}

// fp32 -> bf16 elementwise
__global__ __launch_bounds__(256)
void cvt_kernel(const float* __restrict__ in, ushort_t* __restrict__ out, int n4)
{
    const int i = blockIdx.x * 256 + threadIdx.x;
    if (i < n4) {
        const float4 f = ((const float4*)in)[i];
        ushort4 o;
        o.x = f2bf(f.x); o.y = f2bf(f.y); o.z = f2bf(f.z); o.w = f2bf(f.w);
        ((ushort4*)out)[i] = o;
    }
}

// ---------------------------------------------------------------------------
// V transpose per head: vb[b*L+j][h*64+d] -> vt[(b*12+h)*64+d][j]
// ---------------------------------------------------------------------------
__global__ __launch_bounds__(256)
void vtrans_kernel(const ushort_t* __restrict__ vb, ushort_t* __restrict__ vt)
{
    const int bh = blockIdx.x;
    const int b = bh / kNH, h = bh - b * kNH;
    const int j0 = blockIdx.y * 64;
    __shared__ ushort_t T[64][72];

    const int tid = threadIdx.x;
    {
        const int jr = tid & 63;
        const int c0 = (tid >> 6) * 16;
        const ushort_t* sp = vb + (size_t)(b * kL + j0 + jr) * kD + h * kDK + c0;
        uint4 u0 = *(const uint4*)sp;
        uint4 u1 = *(const uint4*)(sp + 8);
        const ushort_t* e0 = (const ushort_t*)&u0;
        const ushort_t* e1 = (const ushort_t*)&u1;
        #pragma unroll
        for (int jj = 0; jj < 8; ++jj) {
            T[c0 + jj][jr]     = e0[jj];
            T[c0 + 8 + jj][jr] = e1[jj];
        }
    }
    __syncthreads();
    {
        const int dr = tid >> 2;
        const int jc = (tid & 3) * 16;
        ushort_t* dp = vt + (size_t)(bh * 64 + dr) * kL + j0 + jc;
        *(uint4*)dp       = *(const uint4*)&T[dr][jc];
        *(uint4*)(dp + 8) = *(const uint4*)&T[dr][jc + 8];
    }
}

// ---------------------------------------------------------------------------
// Relative-position bias table, all heads at once.
// ---------------------------------------------------------------------------
__global__ __launch_bounds__(256)
void bias_kernel(const float* __restrict__ sx, const float* __restrict__ sy,
                 const float* __restrict__ P1, const float* __restrict__ pb1,
                 const float* __restrict__ P2, const float* __restrict__ pb2,
                 ushort_t* __restrict__ biasb)
{
    const int bid = blockIdx.x;
    const int b = bid >> 12;
    const int i = (bid >> 2) & 1023;
    const int j = (bid & 3) * 256 + threadIdx.x;
    const int tid = threadIdx.x;

    __shared__ float A1[32], B1[32], C1[32], W2l[384], pb2l[12];
    if (tid < 32) { A1[tid] = P1[tid]; B1[tid] = P1[32 + tid]; C1[tid] = pb1[tid]; }
    if (tid < 12) pb2l[tid] = pb2[tid];
    for (int e = tid; e < 384; e += 256) W2l[e] = P2[e];
    __syncthreads();

    const float xi = sx[b * kL + i], yi = sy[b * kL + i];
    float rx = xi - sx[b * kL + j];
    float ry = yi - sy[b * kL + j];
    rx = fminf(fmaxf(rx, -1000.f), 1000.f) * 1e-3f;
    ry = fminf(fmaxf(ry, -1000.f), 1000.f) * 1e-3f;

    float acc[12] = {};
    #pragma unroll
    for (int u = 0; u < 32; ++u) {
        float t = fmaf(rx, A1[u], fmaf(ry, B1[u], C1[u]));
        t = fmaxf(t, 0.f);
        #pragma unroll
        for (int h = 0; h < 12; ++h)
            acc[h] = fmaf(t, W2l[u * 12 + h], acc[h]);
    }
    #pragma unroll
    for (int h = 0; h < 12; ++h)
        biasb[((size_t)(b * kNH + h) * kL + i) * kL + j] = f2bf(acc[h] + pb2l[h]);
}

// ---------------------------------------------------------------------------
// MFMA flash attention. 1 wave/block, 16 q-rows, K-tiles of 64.
// ---------------------------------------------------------------------------
__global__ __launch_bounds__(64)
void attn_kernel(const ushort_t* __restrict__ qg, const ushort_t* __restrict__ kg,
                 const ushort_t* __restrict__ vt, const ushort_t* __restrict__ biasb,
                 ushort_t* __restrict__ og)
{
    const int bh = blockIdx.x;
    const int b  = bh / kNH, h = bh - b * kNH;
    const int q0 = blockIdx.y * 16;
    const int lane = threadIdx.x;
    const int fl = lane & 15, fq = lane >> 4;

    __shared__ ushort_t Sp[16][72];

    const size_t qoff = (size_t)(b * kL + q0 + fl) * kD + h * kDK + fq * 8;
    const bf16x8 aq0 = *(const bf16x8*)(qg + qoff);
    const bf16x8 aq1 = *(const bf16x8*)(qg + qoff + 32);

    const ushort_t* kbase = kg + (size_t)(b * kL) * kD + h * kDK;
    const ushort_t* vbase = vt + (size_t)(bh * 64) * kL;
    const ushort_t* bbase = biasb + ((size_t)bh * kL + q0) * kL;

    f32x4 accO[4] = {};
    float m_run[4] = {-INFINITY, -INFINITY, -INFINITY, -INFINITY};
    float l_run[4] = {};

    for (int k0 = 0; k0 < kL; k0 += 64) {
        float bvals[4][4];
        #pragma unroll
        for (int r = 0; r < 4; ++r)
            #pragma unroll
            for (int n = 0; n < 4; ++n)
                bvals[n][r] = bf2f(bbase[(size_t)(fq * 4 + r) * kL + k0 + n * 16 + fl]);

        f32x4 S[4] = {};
        #pragma unroll
        for (int n = 0; n < 4; ++n) {
            const ushort_t* kr = kbase + (size_t)(k0 + n * 16 + fl) * kD + fq * 8;
            const bf16x8 bk0 = *(const bf16x8*)kr;
            const bf16x8 bk1 = *(const bf16x8*)(kr + 32);
            S[n] = __builtin_amdgcn_mfma_f32_16x16x32_bf16(aq0, bk0, S[n], 0, 0, 0);
            S[n] = __builtin_amdgcn_mfma_f32_16x16x32_bf16(aq1, bk1, S[n], 0, 0, 0);
        }
        #pragma unroll
        for (int n = 0; n < 4; ++n)
            #pragma unroll
            for (int r = 0; r < 4; ++r)
                S[n][r] = fmaf(S[n][r], 0.125f, bvals[n][r]);

        #pragma unroll
        for (int r = 0; r < 4; ++r) {
            float mx = fmaxf(fmaxf(S[0][r], S[1][r]), fmaxf(S[2][r], S[3][r]));
            mx = fmaxf(mx, __shfl_xor(mx, 1, 16));
            mx = fmaxf(mx, __shfl_xor(mx, 2, 16));
            mx = fmaxf(mx, __shfl_xor(mx, 4, 16));
            mx = fmaxf(mx, __shfl_xor(mx, 8, 16));
            const float mnew  = fmaxf(m_run[r], mx);
            const float alpha = __expf(m_run[r] - mnew);
            float ls = 0.f;
            #pragma unroll
            for (int n = 0; n < 4; ++n) {
                const float e = __expf(S[n][r] - mnew);
                S[n][r] = e;
                ls += e;
            }
            ls += __shfl_xor(ls, 1, 16);
            ls += __shfl_xor(ls, 2, 16);
            ls += __shfl_xor(ls, 4, 16);
            ls += __shfl_xor(ls, 8, 16);
            l_run[r] = l_run[r] * alpha + ls;
            m_run[r] = mnew;
            #pragma unroll
            for (int n = 0; n < 4; ++n) accO[n][r] *= alpha;
        }

        #pragma unroll
        for (int n = 0; n < 4; ++n)
            #pragma unroll
            for (int r = 0; r < 4; ++r)
                Sp[fq * 4 + r][n * 16 + fl] = f2bf(S[n][r]);
        __syncthreads();

        const bf16x8 ap0 = *(const bf16x8*)&Sp[fl][fq * 8];
        const bf16x8 ap1 = *(const bf16x8*)&Sp[fl][32 + fq * 8];
        #pragma unroll
        for (int n = 0; n < 4; ++n) {
            const ushort_t* vr = vbase + (size_t)(n * 16 + fl) * kL + k0 + fq * 8;
            const bf16x8 bv0 = *(const bf16x8*)vr;
            const bf16x8 bv1 = *(const bf16x8*)(vr + 32);
            accO[n] = __builtin_amdgcn_mfma_f32_16x16x32_bf16(ap0, bv0, accO[n], 0, 0, 0);
            accO[n] = __builtin_amdgcn_mfma_f32_16x16x32_bf16(ap1, bv1, accO[n], 0, 0, 0);
        }
        __syncthreads();
    }

    float inv[4];
    #pragma unroll
    for (int r = 0; r < 4; ++r) inv[r] = 1.0f / l_run[r];
    #pragma unroll
    for (int n = 0; n < 4; ++n)
        #pragma unroll
        for (int r = 0; r < 4; ++r)
            og[(size_t)(b * kL + q0 + fq * 4 + r) * kD + h * kDK + n * 16 + fl] =
                f2bf(accO[n][r] * inv[r]);
}

// ---------------------------------------------------------------------------
// Residual + split-K reduce + bias + LayerNorm.
//   pre[d] = a[row,d] + bias[d] + sum_p parts[p][row,d];  out = LN(pre)*g+be
// ---------------------------------------------------------------------------
template<int NPART, int DUAL>
__global__ __launch_bounds__(256)
void ln_kernel(const float* __restrict__ a, const float* __restrict__ parts,
               const float* __restrict__ bias,
               const float* __restrict__ g, const float* __restrict__ be,
               float* __restrict__ out, ushort_t* __restrict__ out_bf)
{
    const int row = blockIdx.x;
    const int tid = threadIdx.x;
    const float* pa = a + (size_t)row * kD;
    constexpr size_t NTOK = (size_t)kRows * kD;

    float v[3];
    float s = 0.f, sq = 0.f;
    #pragma unroll
    for (int i = 0; i < 3; ++i) {
        const int d = tid + i * 256;
        float t = pa[d] + bias[d];
        #pragma unroll
        for (int p = 0; p < NPART; ++p)
            t += parts[p * NTOK + (size_t)row * kD + d];
        v[i] = t;
        s  += t;
        sq += t * t;
    }
    #pragma unroll
    for (int off = 32; off > 0; off >>= 1) {
        s  += __shfl_down(s, off);
        sq += __shfl_down(sq, off);
    }
    __shared__ float bs[4], bq2[4];
    if ((tid & 63) == 0) { bs[tid >> 6] = s; bq2[tid >> 6] = sq; }
    __syncthreads();
    const float ts = bs[0] + bs[1] + bs[2] + bs[3];
    const float tq = bq2[0] + bq2[1] + bq2[2] + bq2[3];
    const float invn = 1.0f / (float)kD;
    const float mean = ts * invn;
    const float var  = tq * invn - mean * mean;
    const float rstd = rsqrtf(var + kEPS);

    float* po = out + (size_t)row * kD;
    #pragma unroll
    for (int i = 0; i < 3; ++i) {
        const int d = tid + i * 256;
        const float o = (v[i] - mean) * rstd * g[d] + be[d];
        po[d] = o;
        if (DUAL) out_bf[(size_t)row * kD + d] = f2bf(o);
    }
}

// ---------------------------------------------------------------------------
extern "C" void kernel_launch(void* const* d_in, const int* in_sizes, int n_in,
                              void* d_out, int out_size, void* d_ws, size_t ws_size,
                              hipStream_t stream)
{
    const float* src = (const float*)d_in[0];
    const float* sx  = (const float*)d_in[1];
    const float* sy  = (const float*)d_in[2];
    const float* Wq  = (const float*)d_in[3];  const float* bq  = (const float*)d_in[4];
    const float* Wk  = (const float*)d_in[5];  const float* bk  = (const float*)d_in[6];
    const float* Wv  = (const float*)d_in[7];  const float* bv  = (const float*)d_in[8];
    const float* Wo  = (const float*)d_in[9];  const float* bo  = (const float*)d_in[10];
    const float* P1  = (const float*)d_in[11]; const float* pb1 = (const float*)d_in[12];
    const float* P2  = (const float*)d_in[13]; const float* pb2 = (const float*)d_in[14];
    const float* W1  = (const float*)d_in[15]; const float* b1  = (const float*)d_in[16];
    const float* W2  = (const float*)d_in[17]; const float* b2  = (const float*)d_in[18];
    const float* g1  = (const float*)d_in[19]; const float* be1 = (const float*)d_in[20];
    const float* g2  = (const float*)d_in[21]; const float* be2 = (const float*)d_in[22];

    // ---- workspace arena (ushort units) ----
    constexpr size_t W768  = 768u * 768u;           // 589824
    constexpr size_t W3072 = 768u * 3072u;          // 2359296
    constexpr size_t NTOK  = (size_t)kRows * kD;    // 1572864

    ushort_t* wsu = (ushort_t*)d_ws;
    ushort_t* wqT = wsu;
    ushort_t* wkT = wqT + W768;
    ushort_t* wvT = wkT + W768;
    ushort_t* qb  = wvT + W768;
    ushort_t* kb  = qb + NTOK;
    ushort_t* vb  = kb + NTOK;
    ushort_t* sb  = vb + NTOK;           // src_bf -> attn out
    ushort_t* vtb = sb + NTOK;
    ushort_t* biasb = vtb + NTOK;        // 50 MB bias region; reused after attn:
    ushort_t* woT   = biasb;                        // 1.18 MB
    ushort_t* w1T   = woT + W768;                   // 4.72 MB
    ushort_t* w2T   = w1T + W3072;                  // 4.72 MB
    float*    xb    = (float*)(w2T + W3072);        // 6.29 MB (fp32 x, live to LN2)
    ushort_t* h1bf  = (ushort_t*)(xb + NTOK);       // 12.6 MB (FFN hidden bf16)
    float*    s2p   = (float*)h1bf;                 // alias: o-proj partials (2x), dead before FFN1
    float*    ff2p  = (float*)(h1bf + 4 * NTOK);    // 18.9 MB (FFN2 partials, 3x fp32)
    ushort_t* xbf   = qb;                // bf16 x (qb dead after attn)

    const dim3 blk(256);

    // 1. early weight transposes (q,k,v) + src->bf16 + bias table
    WtArgs wa_early;
    wa_early.d[0] = { Wq, wqT, kD, kD };
    wa_early.d[1] = { Wk, wkT, kD, kD };
    wa_early.d[2] = { Wv, wvT, kD, kD };
    wt_kernel<<<dim3(144, 1, 3), blk, 0, stream>>>(wa_early);
    cvt_kernel<<<dim3((int)(NTOK / 4 / 256)), blk, 0, stream>>>(src, sb, (int)(NTOK / 4));
    bias_kernel<<<dim3(8192), blk, 0, stream>>>(sx, sy, P1, pb1, P2, pb2, biasb);

    // 2. QKV projection
    gemm_qkv_kernel<<<dim3(kD / 128, kRows / 128, 3), blk, 0, stream>>>(
        sb, wqT, wkT, wvT, bq, bk, bv, qb, kb, vb);

    // 3. V transpose per head
    vtrans_kernel<<<dim3(2 * kNH, kL / 64), blk, 0, stream>>>(vb, vtb);

    // 4. MFMA flash attention (writes bf16 into sb)
    attn_kernel<<<dim3(2 * kNH, kL / 16), dim3(64), 0, stream>>>(qb, kb, vtb, biasb, sb);

    // 5. late weight transposes into the now-dead bias region
    WtArgs wa_late;
    wa_late.d[0] = { Wo, woT, kD,  kD  };
    wa_late.d[1] = { W1, w1T, kD,  kFF };
    wa_late.d[2] = { W2, w2T, kFF, kD  };
    wt_kernel<<<dim3(576, 1, 3), blk, 0, stream>>>(wa_late);

    // 6. out-projection, split-K=2 (192 blocks) -> fp32 partials
    gemm_splitk_kernel<<<dim3(kD / 128, kRows / 128, 2), blk, 0, stream>>>(
        sb, woT, s2p, kD, kD, kD / 2);

    // 7. LN1: x = LN(src + bo + sum partials), fp32 + bf16
    ln_kernel<2, 1><<<dim3(kRows), blk, 0, stream>>>(src, s2p, bo, g1, be1, xb, xbf);

    // 8. FFN1: relu(x @ W1 + b1) -> bf16 (384 blocks)
    gemm_kernel<1, 1><<<dim3(kFF / 128, kRows / 128), blk, 0, stream>>>(
        xbf, w1T, b1, h1bf, kFF, kD);

    // 9. FFN2, split-K=3 (288 blocks) -> fp32 partials
    gemm_splitk_kernel<<<dim3(kD / 128, kRows / 128, 3), blk, 0, stream>>>(
        h1bf, w2T, ff2p, kD, kFF, kFF / 3);

    // 10. LN2: out = LN(x + b2 + sum partials)
    ln_kernel<3, 0><<<dim3(kRows), blk, 0, stream>>>(xb, ff2p, b2, g2, be2,
                                                     (float*)d_out, nullptr);
}